// Round 1
// baseline (413.865 us; speedup 1.0000x reference)
//
#include <hip/hip_runtime.h>
#include <hip/hip_bf16.h>

#define Bn 16
#define Sn 512
#define Hn 768
#define Ln 4096

typedef __attribute__((ext_vector_type(8))) short bf16x8;
typedef __attribute__((ext_vector_type(4))) float f32x4;

using bf16 = __hip_bfloat16;

constexpr int BL = 64;        // l-rows per block
constexpr int KH = 32;        // phase2 k-chunk over H
constexpr int NH = 128;       // phase5 n-chunk over H
constexpr int KS = 32;        // phase5 k-chunk over S
constexpr int XP = KH + 8;    // 40 bf16 pitch (pad kills bank conflicts, keeps 16B align)
constexpr int TP = KS + 8;    // 40
constexpr int PP = Sn + 8;    // 520 (1040B rows, 16B aligned)

union Pack8 { bf16 h[8]; uint4 u; };

__device__ inline uint4 cvt8(float4 a, float4 b) {
  Pack8 p;
  p.h[0] = __float2bfloat16(a.x); p.h[1] = __float2bfloat16(a.y);
  p.h[2] = __float2bfloat16(a.z); p.h[3] = __float2bfloat16(a.w);
  p.h[4] = __float2bfloat16(b.x); p.h[5] = __float2bfloat16(b.y);
  p.h[6] = __float2bfloat16(b.z); p.h[7] = __float2bfloat16(b.w);
  return p.u;
}

// ---- pre-kernel: X fp32 -> bf16 row-major AND bf16 transposed [B][H][S] ----
__global__ __launch_bounds__(256) void convert_x_kernel(
    const float* __restrict__ X, bf16* __restrict__ Xbf, bf16* __restrict__ XT) {
  __shared__ bf16 t[64][72];
  const int tid = threadIdx.x;
  const int b  = blockIdx.z;
  const int s0 = blockIdx.y * 64;
  const int h0 = blockIdx.x * 64;
  const int r = tid >> 2;
  const int p = tid & 3;
  const float* src = X + ((size_t)b * Sn + s0 + r) * Hn + h0 + p * 16;
  float4 a0 = *(const float4*)(src + 0);
  float4 a1 = *(const float4*)(src + 4);
  float4 a2 = *(const float4*)(src + 8);
  float4 a3 = *(const float4*)(src + 12);
  uint4 u0 = cvt8(a0, a1);
  uint4 u1 = cvt8(a2, a3);
  bf16* xb = Xbf + ((size_t)b * Sn + s0 + r) * Hn + h0 + p * 16;
  *(uint4*)(xb)     = u0;
  *(uint4*)(xb + 8) = u1;
  *(uint4*)&t[r][p * 16]     = u0;
  *(uint4*)&t[r][p * 16 + 8] = u1;
  __syncthreads();
  Pack8 o0, o1;
#pragma unroll
  for (int i = 0; i < 8; ++i) {
    o0.h[i] = t[p * 16 + i][r];
    o1.h[i] = t[p * 16 + 8 + i][r];
  }
  bf16* xt = XT + ((size_t)b * Hn + h0 + r) * Sn + s0 + p * 16;
  *(uint4*)(xt)     = o0.u;
  *(uint4*)(xt + 8) = o1.u;
}

// ---- pre-kernel: W fp32 -> bf16 ----
__global__ __launch_bounds__(256) void convert_w_kernel(
    const float* __restrict__ W, bf16* __restrict__ Wbf) {
  const size_t i = ((size_t)blockIdx.x * 256 + threadIdx.x) * 8;
  float4 a0 = *(const float4*)(W + i);
  float4 a1 = *(const float4*)(W + i + 4);
  *(uint4*)(Wbf + i) = cvt8(a0, a1);
}

// ---- fused main kernel: scores -> softmax -> PV ----
__global__ __launch_bounds__(256, 2) void attn_main_kernel(
    const int* __restrict__ masks,
    const bf16* __restrict__ Xbf, const bf16* __restrict__ XTg,
    const bf16* __restrict__ Wbf, float* __restrict__ out) {
  __shared__ float bias[Sn];
  __shared__ union {
    struct { bf16 Xs[Sn][XP]; bf16 Ws[BL][XP]; } p2;   // 46080 B
    struct { bf16 P[BL][PP];  bf16 XT[NH][TP]; } p5;   // 76800 B
  } sm;
  const int tid  = threadIdx.x;
  const int wv   = tid >> 6;
  const int lane = tid & 63;
  const int col  = lane & 15;    // MFMA n / D-col
  const int quad = lane >> 4;
  const int b  = blockIdx.x / (Ln / BL);
  const int l0 = (blockIdx.x % (Ln / BL)) * BL;
  const int r4    = tid & 3;
  const int row64 = tid >> 2;

  // mask -> additive bias
  for (int i = tid; i < Sn; i += 256)
    bias[i] = masks[b * Sn + i] ? 0.0f : -1e30f;

  const f32x4 zero = {0.f, 0.f, 0.f, 0.f};
  f32x4 acc[32];
#pragma unroll
  for (int i = 0; i < 32; ++i) acc[i] = zero;

  // ---- phase 2: scores[64l x 512s], K over H ----
  for (int k0 = 0; k0 < Hn; k0 += KH) {
    __syncthreads();
#pragma unroll
    for (int s8 = 0; s8 < 8; ++s8) {
      const int row = s8 * 64 + row64;
      uint4 v = *(const uint4*)(Xbf + ((size_t)b * Sn + row) * Hn + k0 + r4 * 8);
      *(uint4*)&sm.p2.Xs[row][r4 * 8] = v;
    }
    {
      uint4 v = *(const uint4*)(Wbf + (size_t)(l0 + row64) * Hn + k0 + r4 * 8);
      *(uint4*)&sm.p2.Ws[row64][r4 * 8] = v;
    }
    __syncthreads();
    // A = W rows (this wave's 16 l), layout A[m=lane&15][k=quad*8+j]
    bf16x8 af = *(const bf16x8*)&sm.p2.Ws[wv * 16 + col][quad * 8];
#pragma unroll
    for (int nt = 0; nt < 32; ++nt) {
      // B = X^T: B[k=h][n=s], lane reads Xs[s=nt*16+col][h=quad*8+j]
      bf16x8 bfr = *(const bf16x8*)&sm.p2.Xs[nt * 16 + col][quad * 8];
      acc[nt] = __builtin_amdgcn_mfma_f32_16x16x32_bf16(af, bfr, acc[nt], 0, 0, 0);
    }
  }
  __syncthreads();

  // ---- phase 3: masked softmax over s; D row = quad*4+r, col = lane&15 ----
  float mx[4] = {-3e38f, -3e38f, -3e38f, -3e38f};
#pragma unroll
  for (int nt = 0; nt < 32; ++nt) {
    const float bi = bias[nt * 16 + col];
#pragma unroll
    for (int r = 0; r < 4; ++r) {
      acc[nt][r] += bi;
      mx[r] = fmaxf(mx[r], acc[nt][r]);
    }
  }
#pragma unroll
  for (int r = 0; r < 4; ++r) {
    mx[r] = fmaxf(mx[r], __shfl_xor(mx[r], 1, 64));
    mx[r] = fmaxf(mx[r], __shfl_xor(mx[r], 2, 64));
    mx[r] = fmaxf(mx[r], __shfl_xor(mx[r], 4, 64));
    mx[r] = fmaxf(mx[r], __shfl_xor(mx[r], 8, 64));
  }
  float sum[4] = {0.f, 0.f, 0.f, 0.f};
#pragma unroll
  for (int nt = 0; nt < 32; ++nt) {
#pragma unroll
    for (int r = 0; r < 4; ++r) {
      const float e = __expf(acc[nt][r] - mx[r]);
      acc[nt][r] = e;
      sum[r] += e;
    }
  }
#pragma unroll
  for (int r = 0; r < 4; ++r) {
    sum[r] += __shfl_xor(sum[r], 1, 64);
    sum[r] += __shfl_xor(sum[r], 2, 64);
    sum[r] += __shfl_xor(sum[r], 4, 64);
    sum[r] += __shfl_xor(sum[r], 8, 64);
  }
  float rs[4];
#pragma unroll
  for (int r = 0; r < 4; ++r) rs[r] = 1.0f / sum[r];

  // ---- phase 4: P (unnormalized, bf16) via LDS: C-layout -> A-layout ----
#pragma unroll
  for (int nt = 0; nt < 32; ++nt)
#pragma unroll
    for (int r = 0; r < 4; ++r)
      sm.p5.P[wv * 16 + quad * 4 + r][nt * 16 + col] = __float2bfloat16(acc[nt][r]);
  __syncthreads();

  // ---- phase 5: O[16l x 768h] = P[16,512] x X[512,768], K over S ----
  for (int n0 = 0; n0 < Hn; n0 += NH) {
    f32x4 oacc[8];
#pragma unroll
    for (int i = 0; i < 8; ++i) oacc[i] = zero;
    for (int s0 = 0; s0 < Sn; s0 += KS) {
      __syncthreads();
#pragma unroll
      for (int h2 = 0; h2 < 2; ++h2) {
        const int hrow = h2 * 64 + row64;
        uint4 v = *(const uint4*)(XTg + ((size_t)b * Hn + n0 + hrow) * Sn + s0 + r4 * 8);
        *(uint4*)&sm.p5.XT[hrow][r4 * 8] = v;
      }
      __syncthreads();
      // A = P rows: A[m=lane&15][k=s0+quad*8+j]
      bf16x8 af = *(const bf16x8*)&sm.p5.P[wv * 16 + col][s0 + quad * 8];
#pragma unroll
      for (int nt = 0; nt < 8; ++nt) {
        // B = X: B[k=s][n=h], lane reads XT[h=nt*16+col][s'=quad*8+j]
        bf16x8 bfr = *(const bf16x8*)&sm.p5.XT[nt * 16 + col][quad * 8];
        oacc[nt] = __builtin_amdgcn_mfma_f32_16x16x32_bf16(af, bfr, oacc[nt], 0, 0, 0);
      }
    }
#pragma unroll
    for (int nt = 0; nt < 8; ++nt)
#pragma unroll
      for (int r = 0; r < 4; ++r) {
        const int l = l0 + wv * 16 + quad * 4 + r;
        const int h = n0 + nt * 16 + col;
        out[((size_t)b * Ln + l) * Hn + h] = oacc[nt][r] * rs[r];
      }
  }
}

// ---- fallback (ws too small): fp32 wave-per-(b,l), slow but correct ----
__global__ __launch_bounds__(256) void attn_fallback_kernel(
    const float* __restrict__ X, const int* __restrict__ masks,
    const float* __restrict__ W, float* __restrict__ out) {
  __shared__ float sc[4][Sn];
  const int wv = threadIdx.x >> 6, lane = threadIdx.x & 63;
  const int gw = blockIdx.x * 4 + wv;
  const int b = gw / Ln, l = gw % Ln;
  float wreg[12];
#pragma unroll
  for (int j = 0; j < 12; ++j) wreg[j] = W[(size_t)l * Hn + j * 64 + lane];
  for (int s = 0; s < Sn; ++s) {
    const float* xr = X + ((size_t)b * Sn + s) * Hn;
    float p = 0.f;
#pragma unroll
    for (int j = 0; j < 12; ++j) p += xr[j * 64 + lane] * wreg[j];
#pragma unroll
    for (int off = 32; off > 0; off >>= 1) p += __shfl_xor(p, off, 64);
    if (lane == 0) sc[wv][s] = p;
  }
  __syncthreads();
  float m = -3e38f;
#pragma unroll
  for (int i = 0; i < 8; ++i) {
    const int s = lane * 8 + i;
    const float v = sc[wv][s] + (masks[b * Sn + s] ? 0.f : -1e30f);
    sc[wv][s] = v;
    m = fmaxf(m, v);
  }
#pragma unroll
  for (int off = 32; off > 0; off >>= 1) m = fmaxf(m, __shfl_xor(m, off, 64));
  __syncthreads();
  float sum = 0.f;
#pragma unroll
  for (int i = 0; i < 8; ++i) {
    const int s = lane * 8 + i;
    const float e = __expf(sc[wv][s] - m);
    sc[wv][s] = e;
    sum += e;
  }
#pragma unroll
  for (int off = 32; off > 0; off >>= 1) sum += __shfl_xor(sum, off, 64);
  const float rs = 1.0f / sum;
  __syncthreads();
  float o[12];
#pragma unroll
  for (int j = 0; j < 12; ++j) o[j] = 0.f;
  for (int s = 0; s < Sn; ++s) {
    const float p = sc[wv][s];
    const float* xr = X + ((size_t)b * Sn + s) * Hn;
#pragma unroll
    for (int j = 0; j < 12; ++j) o[j] += p * xr[j * 64 + lane];
  }
#pragma unroll
  for (int j = 0; j < 12; ++j)
    out[((size_t)b * Ln + l) * Hn + j * 64 + lane] = o[j] * rs;
}

extern "C" void kernel_launch(void* const* d_in, const int* in_sizes, int n_in,
                              void* d_out, int out_size, void* d_ws, size_t ws_size,
                              hipStream_t stream) {
  const float* X     = (const float*)d_in[0];
  const int*   masks = (const int*)d_in[1];
  const float* W     = (const float*)d_in[2];
  float* out = (float*)d_out;

  const size_t need = ((size_t)2 * Bn * Sn * Hn + (size_t)Ln * Hn) * sizeof(bf16);
  if (ws_size >= need) {
    bf16* Xbf = (bf16*)d_ws;
    bf16* XT  = Xbf + (size_t)Bn * Sn * Hn;
    bf16* Wbf = XT  + (size_t)Bn * Sn * Hn;
    convert_x_kernel<<<dim3(Hn / 64, Sn / 64, Bn), 256, 0, stream>>>(X, Xbf, XT);
    convert_w_kernel<<<dim3((Ln * Hn) / 2048), 256, 0, stream>>>(W, Wbf);
    attn_main_kernel<<<dim3(Bn * (Ln / BL)), 256, 0, stream>>>(masks, Xbf, XT, Wbf, out);
  } else {
    attn_fallback_kernel<<<dim3(Bn * Ln / 4), 256, 0, stream>>>(X, masks, W, out);
  }
}

// Round 3
// 370.785 us; speedup vs baseline: 1.1162x; 1.1162x over previous
//
#include <hip/hip_runtime.h>
#include <hip/hip_bf16.h>

#define Bn 16
#define Sn 512
#define Hn 768
#define Ln 4096

typedef __attribute__((ext_vector_type(8))) short bf16x8;
typedef __attribute__((ext_vector_type(4))) float f32x4;

using bf16 = __hip_bfloat16;

constexpr int BL = 64;   // l-rows per block

// ---- LDS layout (time-multiplexed, offsets in bytes) ----
// phase2:  Xs [512 rows][64 B]    @ 0       (32768)  row = s, 32 k bf16
//          Ws [ 64 rows][64 B]    @ 32768   (4096)   row = l-local
// softmax: redm[2][64] f32        @ 65536   (512)
//          reds[2][64] f32        @ 66048   (512)
// phase5:  P  [64 rows][1024 B]   @ 0       (65536)  16B chunks XOR-swizzled: slot = chunk ^ (row&7)
//          XT [128 rows][128 B]   @ 65536   (16384)  row = h-local, chunks XOR-swizzled same way
constexpr int SM_BYTES = 81920;  // 2 blocks/CU
constexpr int XS_OFF   = 0;
constexpr int WS_OFF   = 32768;
constexpr int P_OFF    = 0;
constexpr int XT_OFF   = 65536;
constexpr int REDM_OFF = 65536;
constexpr int REDS_OFF = 66048;

typedef const __attribute__((address_space(1))) unsigned int* gas_ptr;
typedef __attribute__((address_space(3))) unsigned int* las_ptr;

__device__ __forceinline__ void gld_lds16(const void* g, void* l) {
  // async 16B/lane global->LDS DMA; LDS dest = wave-uniform base + lane*16
  __builtin_amdgcn_global_load_lds((gas_ptr)g, (las_ptr)l, 16, 0, 0);
}

__device__ __forceinline__ unsigned short bfbits(float x) {
  __hip_bfloat16 h = __float2bfloat16(x);
  unsigned short u;
  __builtin_memcpy(&u, &h, 2);
  return u;
}

union Pack8 { bf16 h[8]; uint4 u; };

__device__ inline uint4 cvt8(float4 a, float4 b) {
  Pack8 p;
  p.h[0] = __float2bfloat16(a.x); p.h[1] = __float2bfloat16(a.y);
  p.h[2] = __float2bfloat16(a.z); p.h[3] = __float2bfloat16(a.w);
  p.h[4] = __float2bfloat16(b.x); p.h[5] = __float2bfloat16(b.y);
  p.h[6] = __float2bfloat16(b.z); p.h[7] = __float2bfloat16(b.w);
  return p.u;
}

// ---- pre-kernel: X fp32 -> bf16 row-major AND bf16 transposed [B][H][S] ----
__global__ __launch_bounds__(256) void convert_x_kernel(
    const float* __restrict__ X, bf16* __restrict__ Xbf, bf16* __restrict__ XT) {
  __shared__ bf16 t[64][72];
  const int tid = threadIdx.x;
  const int b  = blockIdx.z;
  const int s0 = blockIdx.y * 64;
  const int h0 = blockIdx.x * 64;
  const int r = tid >> 2;
  const int p = tid & 3;
  const float* src = X + ((size_t)b * Sn + s0 + r) * Hn + h0 + p * 16;
  float4 a0 = *(const float4*)(src + 0);
  float4 a1 = *(const float4*)(src + 4);
  float4 a2 = *(const float4*)(src + 8);
  float4 a3 = *(const float4*)(src + 12);
  uint4 u0 = cvt8(a0, a1);
  uint4 u1 = cvt8(a2, a3);
  bf16* xb = Xbf + ((size_t)b * Sn + s0 + r) * Hn + h0 + p * 16;
  *(uint4*)(xb)     = u0;
  *(uint4*)(xb + 8) = u1;
  *(uint4*)&t[r][p * 16]     = u0;
  *(uint4*)&t[r][p * 16 + 8] = u1;
  __syncthreads();
  Pack8 o0, o1;
#pragma unroll
  for (int i = 0; i < 8; ++i) {
    o0.h[i] = t[p * 16 + i][r];
    o1.h[i] = t[p * 16 + 8 + i][r];
  }
  bf16* xt = XT + ((size_t)b * Hn + h0 + r) * Sn + s0 + p * 16;
  *(uint4*)(xt)     = o0.u;
  *(uint4*)(xt + 8) = o1.u;
}

// ---- pre-kernel: W fp32 -> bf16 ----
__global__ __launch_bounds__(256) void convert_w_kernel(
    const float* __restrict__ W, bf16* __restrict__ Wbf) {
  const size_t i = ((size_t)blockIdx.x * 256 + threadIdx.x) * 8;
  float4 a0 = *(const float4*)(W + i);
  float4 a1 = *(const float4*)(W + i + 4);
  *(uint4*)(Wbf + i) = cvt8(a0, a1);
}

// ---- fused main kernel ----
// wave w: lg = w>>1 owns l rows lg*32..+31; sg = w&1 owns s half sg*256..+255 (phase2)
//         and nt-parity sg of each 128-h chunk (phase5)
__global__ __launch_bounds__(256, 2) void attn_main_kernel(
    const int* __restrict__ masks,
    const bf16* __restrict__ Xbf, const bf16* __restrict__ XTg,
    const bf16* __restrict__ Wbf, float* __restrict__ out) {
  __shared__ char sm[SM_BYTES];
  const int tid  = threadIdx.x;
  const int w    = tid >> 6;
  const int lane = tid & 63;
  const int col  = lane & 15;
  const int quad = lane >> 4;
  const int lg   = w >> 1;
  const int sg   = w & 1;
  const int b  = blockIdx.x / (Ln / BL);
  const int l0 = (blockIdx.x % (Ln / BL)) * BL;

  // mask bias -> 16 regs (this lane's 16 s-columns within its half)
  float bias_r[16];
  {
    const int* mrow = masks + b * Sn + sg * 256 + col;
#pragma unroll
    for (int nt = 0; nt < 16; ++nt)
      bias_r[nt] = mrow[nt * 16] ? 0.0f : -1e30f;
  }

  const f32x4 zero = {0.f, 0.f, 0.f, 0.f};
  f32x4 acc[2][16];
#pragma unroll
  for (int a = 0; a < 2; ++a)
#pragma unroll
    for (int nt = 0; nt < 16; ++nt) acc[a][nt] = zero;

  // ---- phase 2: scores[64l x 512s]; wave computes 32l x 256s ----
  for (int k0 = 0; k0 < Hn; k0 += 32) {
    __syncthreads();
    {
      // Xs: wave stages rows w*128..+127 (8 insts x 16 rows x 64B)
      const int r0 = w * 128;
      const bf16* g = Xbf + ((size_t)b * Sn + r0 + (lane >> 2)) * Hn + k0 + (lane & 3) * 8;
#pragma unroll
      for (int i = 0; i < 8; ++i) {
        gld_lds16(g, &sm[XS_OFF + (r0 + i * 16) * 64]);
        g += 16 * Hn;
      }
      // Ws: wave stages rows w*16..+15
      const bf16* gw = Wbf + ((size_t)(l0 + w * 16 + (lane >> 2))) * Hn + k0 + (lane & 3) * 8;
      gld_lds16(gw, &sm[WS_OFF + (w * 16) * 64]);
    }
    __syncthreads();
    bf16x8 a0 = *(const bf16x8*)&sm[WS_OFF + (lg * 32 + col) * 64 + quad * 16];
    bf16x8 a1 = *(const bf16x8*)&sm[WS_OFF + (lg * 32 + 16 + col) * 64 + quad * 16];
#pragma unroll
    for (int nt = 0; nt < 16; ++nt) {
      bf16x8 bf_ = *(const bf16x8*)&sm[XS_OFF + (sg * 256 + nt * 16 + col) * 64 + quad * 16];
      acc[0][nt] = __builtin_amdgcn_mfma_f32_16x16x32_bf16(a0, bf_, acc[0][nt], 0, 0, 0);
      acc[1][nt] = __builtin_amdgcn_mfma_f32_16x16x32_bf16(a1, bf_, acc[1][nt], 0, 0, 0);
    }
  }

  // ---- phase 3: masked softmax, cross-wave (s split over sg) ----
  float* redm = (float*)&sm[REDM_OFF];
  float* reds = (float*)&sm[REDS_OFF];
  float mx[2][4];
#pragma unroll
  for (int a = 0; a < 2; ++a)
#pragma unroll
    for (int r = 0; r < 4; ++r) mx[a][r] = -3e38f;
#pragma unroll
  for (int a = 0; a < 2; ++a)
#pragma unroll
    for (int nt = 0; nt < 16; ++nt)
#pragma unroll
      for (int r = 0; r < 4; ++r) {
        acc[a][nt][r] += bias_r[nt];
        mx[a][r] = fmaxf(mx[a][r], acc[a][nt][r]);
      }
#pragma unroll
  for (int a = 0; a < 2; ++a)
#pragma unroll
    for (int r = 0; r < 4; ++r) {
      mx[a][r] = fmaxf(mx[a][r], __shfl_xor(mx[a][r], 1, 64));
      mx[a][r] = fmaxf(mx[a][r], __shfl_xor(mx[a][r], 2, 64));
      mx[a][r] = fmaxf(mx[a][r], __shfl_xor(mx[a][r], 4, 64));
      mx[a][r] = fmaxf(mx[a][r], __shfl_xor(mx[a][r], 8, 64));
    }
  if (col == 0) {
#pragma unroll
    for (int a = 0; a < 2; ++a)
#pragma unroll
      for (int r = 0; r < 4; ++r)
        redm[sg * 64 + lg * 32 + a * 16 + quad * 4 + r] = mx[a][r];
  }
  __syncthreads();
  float gmax[2][4], sum[2][4];
#pragma unroll
  for (int a = 0; a < 2; ++a)
#pragma unroll
    for (int r = 0; r < 4; ++r) {
      const int row = lg * 32 + a * 16 + quad * 4 + r;
      gmax[a][r] = fmaxf(redm[row], redm[64 + row]);
      sum[a][r] = 0.f;
    }
#pragma unroll
  for (int a = 0; a < 2; ++a)
#pragma unroll
    for (int nt = 0; nt < 16; ++nt)
#pragma unroll
      for (int r = 0; r < 4; ++r) {
        const float e = __expf(acc[a][nt][r] - gmax[a][r]);
        acc[a][nt][r] = e;
        sum[a][r] += e;
      }
#pragma unroll
  for (int a = 0; a < 2; ++a)
#pragma unroll
    for (int r = 0; r < 4; ++r) {
      sum[a][r] += __shfl_xor(sum[a][r], 1, 64);
      sum[a][r] += __shfl_xor(sum[a][r], 2, 64);
      sum[a][r] += __shfl_xor(sum[a][r], 4, 64);
      sum[a][r] += __shfl_xor(sum[a][r], 8, 64);
    }
  if (col == 0) {
#pragma unroll
    for (int a = 0; a < 2; ++a)
#pragma unroll
      for (int r = 0; r < 4; ++r)
        reds[sg * 64 + lg * 32 + a * 16 + quad * 4 + r] = sum[a][r];
  }
  __syncthreads();
  float rs[2][4];
#pragma unroll
  for (int a = 0; a < 2; ++a)
#pragma unroll
    for (int r = 0; r < 4; ++r) {
      const int row = lg * 32 + a * 16 + quad * 4 + r;
      rs[a][r] = 1.0f / (reds[row] + reds[64 + row]);
    }

  // ---- phase 4: P (unnormalized exp) -> LDS bf16, b32 packed via shfl pairing ----
  // P row = 1024 B (512 bf16). 16B chunk c of row stored at slot c ^ (row&7).
  const int pi = col & 1;  // parity
#pragma unroll
  for (int a = 0; a < 2; ++a)
#pragma unroll
    for (int t = 0; t < 8; ++t)
#pragma unroll
      for (int r = 0; r < 4; ++r) {
        const float own0 = acc[a][2 * t][r];
        const float own1 = acc[a][2 * t + 1][r];
        const float p0 = __shfl_xor(own0, 1, 64);  // partner's nt=2t value
        const float p1 = __shfl_xor(own1, 1, 64);  // partner's nt=2t+1 value
        const float lo = pi ? p1 : own0;
        const float hi = pi ? own1 : p0;
        const unsigned pk = (unsigned)bfbits(lo) | ((unsigned)bfbits(hi) << 16);
        const int nt_w = 2 * t + pi;
        const int row = lg * 32 + a * 16 + quad * 4 + r;
        const int sp = sg * 256 + nt_w * 16 + (col & ~1);
        const int slot = (sp >> 3) ^ (row & 7);
        *(unsigned*)&sm[P_OFF + row * 1024 + slot * 16 + (sp & 7) * 2] = pk;
      }

  // ---- phase 5: O[64l x 768h] = P[64,512] x X[512,768] ----
  for (int n0 = 0; n0 < Hn / 128; ++n0) {
    f32x4 oacc[2][4];
#pragma unroll
    for (int a = 0; a < 2; ++a)
#pragma unroll
      for (int nt = 0; nt < 4; ++nt) oacc[a][nt] = zero;
    for (int s0 = 0; s0 < Sn; s0 += 64) {
      __syncthreads();
      {
        // XT tile: 128 h-rows x 64 s; wave stages rows w*32..+31 (4 insts x 8 rows x 128B)
        // chunk swizzle at the SOURCE: lane (rr,cc) fetches s-chunk cc^rr so that
        // row rr's chunk c lands at LDS slot c^rr.
        const int r0 = w * 32;
        const int rr = lane >> 3;
        const int cc = lane & 7;
        const bf16* g = XTg + ((size_t)b * Hn + n0 * 128 + r0 + rr) * Sn + s0 + (cc ^ rr) * 8;
#pragma unroll
        for (int i = 0; i < 4; ++i) {
          gld_lds16(g, &sm[XT_OFF + (r0 + i * 8) * 128]);
          g += 8 * Sn;
        }
      }
      __syncthreads();
#pragma unroll
      for (int ks = 0; ks < 2; ++ks) {
        const int chunk = (s0 + ks * 32 + quad * 8) >> 3;
        bf16x8 pa[2];
#pragma unroll
        for (int a = 0; a < 2; ++a) {
          const int row = lg * 32 + a * 16 + col;
          const int slot = chunk ^ (row & 7);
          pa[a] = *(const bf16x8*)&sm[P_OFF + row * 1024 + slot * 16];
        }
#pragma unroll
        for (int nt = 0; nt < 4; ++nt) {
          const int hl = (nt * 2 + sg) * 16 + col;
          const int xslot = (ks * 4 + quad) ^ (hl & 7);
          bf16x8 xb = *(const bf16x8*)&sm[XT_OFF + hl * 128 + xslot * 16];
          oacc[0][nt] = __builtin_amdgcn_mfma_f32_16x16x32_bf16(pa[0], xb, oacc[0][nt], 0, 0, 0);
          oacc[1][nt] = __builtin_amdgcn_mfma_f32_16x16x32_bf16(pa[1], xb, oacc[1][nt], 0, 0, 0);
        }
      }
    }
#pragma unroll
    for (int a = 0; a < 2; ++a)
#pragma unroll
      for (int nt = 0; nt < 4; ++nt) {
        const int h = n0 * 128 + (nt * 2 + sg) * 16 + col;
        const int lbase = l0 + lg * 32 + a * 16 + quad * 4;
#pragma unroll
        for (int r = 0; r < 4; ++r)
          out[((size_t)b * Ln + lbase + r) * Hn + h] = oacc[a][nt][r] * rs[a][r];
      }
  }
}

// ---- fallback (ws too small): fp32 wave-per-(b,l), slow but correct ----
__global__ __launch_bounds__(256) void attn_fallback_kernel(
    const float* __restrict__ X, const int* __restrict__ masks,
    const float* __restrict__ W, float* __restrict__ out) {
  __shared__ float sc[4][Sn];
  const int wv = threadIdx.x >> 6, lane = threadIdx.x & 63;
  const int gw = blockIdx.x * 4 + wv;
  const int b = gw / Ln, l = gw % Ln;
  float wreg[12];
#pragma unroll
  for (int j = 0; j < 12; ++j) wreg[j] = W[(size_t)l * Hn + j * 64 + lane];
  for (int s = 0; s < Sn; ++s) {
    const float* xr = X + ((size_t)b * Sn + s) * Hn;
    float p = 0.f;
#pragma unroll
    for (int j = 0; j < 12; ++j) p += xr[j * 64 + lane] * wreg[j];
#pragma unroll
    for (int off = 32; off > 0; off >>= 1) p += __shfl_xor(p, off, 64);
    if (lane == 0) sc[wv][s] = p;
  }
  __syncthreads();
  float m = -3e38f;
#pragma unroll
  for (int i = 0; i < 8; ++i) {
    const int s = lane * 8 + i;
    const float v = sc[wv][s] + (masks[b * Sn + s] ? 0.f : -1e30f);
    sc[wv][s] = v;
    m = fmaxf(m, v);
  }
#pragma unroll
  for (int off = 32; off > 0; off >>= 1) m = fmaxf(m, __shfl_xor(m, off, 64));
  __syncthreads();
  float sum = 0.f;
#pragma unroll
  for (int i = 0; i < 8; ++i) {
    const int s = lane * 8 + i;
    const float e = __expf(sc[wv][s] - m);
    sc[wv][s] = e;
    sum += e;
  }
#pragma unroll
  for (int off = 32; off > 0; off >>= 1) sum += __shfl_xor(sum, off, 64);
  const float rs = 1.0f / sum;
  __syncthreads();
  float o[12];
#pragma unroll
  for (int j = 0; j < 12; ++j) o[j] = 0.f;
  for (int s = 0; s < Sn; ++s) {
    const float p = sc[wv][s];
    const float* xr = X + ((size_t)b * Sn + s) * Hn;
#pragma unroll
    for (int j = 0; j < 12; ++j) o[j] += p * xr[j * 64 + lane];
  }
#pragma unroll
  for (int j = 0; j < 12; ++j)
    out[((size_t)b * Ln + l) * Hn + j * 64 + lane] = o[j] * rs;
}

extern "C" void kernel_launch(void* const* d_in, const int* in_sizes, int n_in,
                              void* d_out, int out_size, void* d_ws, size_t ws_size,
                              hipStream_t stream) {
  const float* X     = (const float*)d_in[0];
  const int*   masks = (const int*)d_in[1];
  const float* W     = (const float*)d_in[2];
  float* out = (float*)d_out;

  const size_t need = ((size_t)2 * Bn * Sn * Hn + (size_t)Ln * Hn) * sizeof(bf16);
  if (ws_size >= need) {
    bf16* Xbf = (bf16*)d_ws;
    bf16* XT  = Xbf + (size_t)Bn * Sn * Hn;
    bf16* Wbf = XT  + (size_t)Bn * Sn * Hn;
    convert_x_kernel<<<dim3(Hn / 64, Sn / 64, Bn), 256, 0, stream>>>(X, Xbf, XT);
    convert_w_kernel<<<dim3((Ln * Hn) / 2048), 256, 0, stream>>>(W, Wbf);
    attn_main_kernel<<<dim3(Bn * (Ln / BL)), 256, 0, stream>>>(masks, Xbf, XT, Wbf, out);
  } else {
    attn_fallback_kernel<<<dim3(Bn * Ln / 4), 256, 0, stream>>>(X, masks, W, out);
  }
}